// Round 1
// baseline (697.127 us; speedup 1.0000x reference)
//
#include <hip/hip_runtime.h>
#include <stdint.h>
#include <cmath>

typedef unsigned short u16;
typedef unsigned int u32;
typedef __attribute__((ext_vector_type(8))) __bf16 bf16x8;
typedef __attribute__((ext_vector_type(4))) float f32x4;

#define HIDDEN 4096
#define NH 32
#define NKV 8
#define HD 128
#define S_LEN 2048

__device__ __forceinline__ u16 f2bf(float f) {
    u32 x = __float_as_uint(f);
    x += 0x7fff + ((x >> 16) & 1);   // RNE
    return (u16)(x >> 16);
}
__device__ __forceinline__ float bf2f(u16 u) {
    return __uint_as_float(((u32)u) << 16);
}

typedef __attribute__((address_space(1))) const void gv_t;
typedef __attribute__((address_space(3))) void lv_t;
__device__ __forceinline__ void async16(const u16* g, u16* s) {
    __builtin_amdgcn_global_load_lds((gv_t*)g, (lv_t*)s, 16, 0, 0);
}

// ---------------- f32 -> bf16 convert ----------------
__global__ void cvt_bf16(const float* __restrict__ src, u16* __restrict__ dst, int n4) {
    int i = blockIdx.x * 256 + threadIdx.x;
    if (i < n4) {
        float4 v = ((const float4*)src)[i];
        union { u16 u[4]; uint2 w; } pk;
        pk.u[0] = f2bf(v.x); pk.u[1] = f2bf(v.y);
        pk.u[2] = f2bf(v.z); pk.u[3] = f2bf(v.w);
        ((uint2*)dst)[i] = pk.w;
    }
}

// ---------------- bf16 GEMM: C[M,N] = A[M,K] * B[N,K]^T ----------------
// m97 structure: 128x128 tile, BK=64, global_load_lds(16B), 16x16x32 MFMA,
// XOR-swizzled 16B chunks to avoid LDS bank aliasing on ds_read_b128.
template <bool OUT_BF16>
__global__ __launch_bounds__(256, 2) void gemm_bt(
    const u16* __restrict__ A, const u16* __restrict__ B, void* __restrict__ Cv,
    int M, int N, int K)
{
    __shared__ u16 sA[128 * 64];
    __shared__ u16 sB[128 * 64];
    const int tid = threadIdx.x;
    const int w = tid >> 6, lane = tid & 63;
    const int l15 = lane & 15, quad = lane >> 4;
    const int m0 = blockIdx.y * 128, n0 = blockIdx.x * 128;
    const int wm = w & 1, wn = w >> 1;

    f32x4 acc[4][4];
#pragma unroll
    for (int mi = 0; mi < 4; ++mi)
#pragma unroll
        for (int ni = 0; ni < 4; ++ni)
#pragma unroll
            for (int r = 0; r < 4; ++r) acc[mi][ni][r] = 0.f;

    for (int kt = 0; kt < K; kt += 64) {
#pragma unroll
        for (int i = 0; i < 4; ++i) {           // A tile: 1024 chunks of 16B
            int c = (i * 4 + w) * 64 + lane;
            int r = c >> 3, sl = c & 7, g = sl ^ (r & 7);
            async16(A + (size_t)(m0 + r) * K + kt + g * 8, &sA[c * 8]);
        }
#pragma unroll
        for (int i = 0; i < 4; ++i) {           // B tile
            int c = (i * 4 + w) * 64 + lane;
            int r = c >> 3, sl = c & 7, g = sl ^ (r & 7);
            async16(B + (size_t)(n0 + r) * K + kt + g * 8, &sB[c * 8]);
        }
        __syncthreads();
#pragma unroll
        for (int ks = 0; ks < 2; ++ks) {
            bf16x8 af[4], bf[4];
#pragma unroll
            for (int t = 0; t < 4; ++t) {
                int row = wm * 64 + t * 16 + l15;
                int sl = (ks * 4 + quad) ^ (row & 7);
                af[t] = *(const bf16x8*)&sA[row * 64 + sl * 8];
            }
#pragma unroll
            for (int t = 0; t < 4; ++t) {
                int row = wn * 64 + t * 16 + l15;
                int sl = (ks * 4 + quad) ^ (row & 7);
                bf[t] = *(const bf16x8*)&sB[row * 64 + sl * 8];
            }
#pragma unroll
            for (int mi = 0; mi < 4; ++mi)
#pragma unroll
                for (int ni = 0; ni < 4; ++ni)
                    acc[mi][ni] = __builtin_amdgcn_mfma_f32_16x16x32_bf16(
                        af[mi], bf[ni], acc[mi][ni], 0, 0, 0);
        }
        __syncthreads();
    }
    // epilogue: C/D layout col=lane&15, row=quad*4+reg
#pragma unroll
    for (int mi = 0; mi < 4; ++mi) {
        int row = m0 + wm * 64 + mi * 16 + quad * 4;
#pragma unroll
        for (int ni = 0; ni < 4; ++ni) {
            int col = n0 + wn * 64 + ni * 16 + l15;
#pragma unroll
            for (int r = 0; r < 4; ++r) {
                if (OUT_BF16)
                    ((u16*)Cv)[(size_t)(row + r) * N + col] = f2bf(acc[mi][ni][r]);
                else
                    ((float*)Cv)[(size_t)(row + r) * N + col] = acc[mi][ni][r];
            }
        }
    }
}

// ---------------- RoPE (in-place, bf16), f64 phase ----------------
struct DTab { double f[64]; };
__global__ void rope_k(u16* __restrict__ buf, const int* __restrict__ pos,
                       int logH, int total, DTab tab)
{
    int idx = blockIdx.x * 256 + threadIdx.x;
    if (idx >= total) return;
    int d = idx & 63;
    int rest = idx >> 6;           // = s*H + h
    int s = rest >> logH;
    double fr = (double)pos[s] * tab.f[d];
    double sd, cd;
    sincos(fr, &sd, &cd);
    float c = (float)cd, sn = (float)sd;
    u16* p = buf + (size_t)rest * HD + d;
    float x1 = bf2f(p[0]), x2 = bf2f(p[64]);
    p[0]  = f2bf(x1 * c - x2 * sn);
    p[64] = f2bf(x2 * c + x1 * sn);
}

// ---------------- V transpose: [S][8][128] -> [8][128][S] ----------------
__global__ void transpose_v(const u16* __restrict__ v, u16* __restrict__ vt) {
    __shared__ u16 t[32][33];
    int h = blockIdx.z;
    int s0 = blockIdx.x * 32, d0 = blockIdx.y * 32;
    int tx = threadIdx.x & 31, ty = threadIdx.x >> 5;
    for (int i = ty; i < 32; i += 8)
        t[i][tx] = v[((size_t)(s0 + i) * NKV + h) * HD + d0 + tx];
    __syncthreads();
    for (int i = ty; i < 32; i += 8)
        vt[((size_t)h * HD + d0 + i) * S_LEN + s0 + tx] = t[tx][i];
}

// ---------------- flash attention (non-causal, GQA 4:1) ----------------
// block = (head, q-tile of 128). wave w owns q rows [w*32, w*32+32).
// O accumulated as O^T[d][q]; V pre-transposed so PV A-frags are contiguous.
__global__ __launch_bounds__(256, 1) void attn_kernel(
    const u16* __restrict__ Q, const u16* __restrict__ Kb,
    const u16* __restrict__ Vt, u16* __restrict__ O)
{
    __shared__ u16 sK[128 * 128];
    __shared__ u16 sV[128 * 128];
    __shared__ u16 sP[128 * 136];   // +8 pad: conflict-free b128 reads & b16 writes
    __shared__ float sAl[128];

    const float sc = 0.08838834764831845f;   // 1/sqrt(128)
    const int tid = threadIdx.x;
    const int w = tid >> 6, lane = tid & 63;
    const int l15 = lane & 15, quad = lane >> 4;
    const int h = blockIdx.y, q0 = blockIdx.x * 128;
    const int hk = h >> 2;

    // preload Q fragments (A-operand: m=lane&15, k=quad*8+j)
    bf16x8 qf[2][4];
#pragma unroll
    for (int mt = 0; mt < 2; ++mt)
#pragma unroll
        for (int ks = 0; ks < 4; ++ks)
            qf[mt][ks] = *(const bf16x8*)(Q + (size_t)(q0 + w * 32 + mt * 16 + l15) * HIDDEN
                                           + h * HD + ks * 32 + quad * 8);

    f32x4 oc[8][2];
#pragma unroll
    for (int dt = 0; dt < 8; ++dt)
#pragma unroll
        for (int nt = 0; nt < 2; ++nt)
#pragma unroll
            for (int r = 0; r < 4; ++r) oc[dt][nt][r] = 0.f;
    float m_r[2][4], l_r[2][4];
#pragma unroll
    for (int mt = 0; mt < 2; ++mt)
#pragma unroll
        for (int r = 0; r < 4; ++r) { m_r[mt][r] = -1e30f; l_r[mt][r] = 0.f; }

    for (int kb = 0; kb < 16; ++kb) {
        const int k0 = kb * 128;
#pragma unroll
        for (int i = 0; i < 8; ++i) {   // K tile [kidx][d], 2048 chunks
            int c = (i * 4 + w) * 64 + lane;
            int r = c >> 4, sl = c & 15, g = sl ^ (r & 15);
            async16(Kb + (size_t)(k0 + r) * (NKV * HD) + hk * HD + g * 8, &sK[c * 8]);
        }
#pragma unroll
        for (int i = 0; i < 8; ++i) {   // V^T tile [d][kidx]
            int c = (i * 4 + w) * 64 + lane;
            int r = c >> 4, sl = c & 15, g = sl ^ (r & 15);
            async16(Vt + (size_t)(hk * HD + r) * S_LEN + k0 + g * 8, &sV[c * 8]);
        }
        __syncthreads();

        // S = Q K^T  (32 q-rows x 128 k-cols per wave)
        f32x4 sa[2][8];
#pragma unroll
        for (int mt = 0; mt < 2; ++mt)
#pragma unroll
            for (int nt = 0; nt < 8; ++nt)
#pragma unroll
                for (int r = 0; r < 4; ++r) sa[mt][nt][r] = 0.f;
#pragma unroll
        for (int ks = 0; ks < 4; ++ks) {
            bf16x8 kf[8];
#pragma unroll
            for (int nt = 0; nt < 8; ++nt) {
                int row = nt * 16 + l15;
                int sl = (ks * 4 + quad) ^ (row & 15);
                kf[nt] = *(const bf16x8*)&sK[row * 128 + sl * 8];
            }
#pragma unroll
            for (int mt = 0; mt < 2; ++mt)
#pragma unroll
                for (int nt = 0; nt < 8; ++nt)
                    sa[mt][nt] = __builtin_amdgcn_mfma_f32_16x16x32_bf16(
                        qf[mt][ks], kf[nt], sa[mt][nt], 0, 0, 0);
        }

        // online softmax over this chunk (rows are wave-local)
#pragma unroll
        for (int mt = 0; mt < 2; ++mt)
#pragma unroll
            for (int r = 0; r < 4; ++r) {
                float mx = -1e30f;
#pragma unroll
                for (int nt = 0; nt < 8; ++nt) mx = fmaxf(mx, sa[mt][nt][r]);
#pragma unroll
                for (int off = 1; off < 16; off <<= 1)
                    mx = fmaxf(mx, __shfl_xor(mx, off, 16));
                float mnew = fmaxf(m_r[mt][r], mx * sc);
                float alpha = __expf(m_r[mt][r] - mnew);
                m_r[mt][r] = mnew;
                float rs = 0.f;
                int qrow = w * 32 + mt * 16 + quad * 4 + r;
#pragma unroll
                for (int nt = 0; nt < 8; ++nt) {
                    float p = __expf(sa[mt][nt][r] * sc - mnew);
                    rs += p;
                    sP[qrow * 136 + nt * 16 + l15] = f2bf(p);
                }
#pragma unroll
                for (int off = 1; off < 16; off <<= 1)
                    rs += __shfl_xor(rs, off, 16);
                l_r[mt][r] = l_r[mt][r] * alpha + rs;
                if (l15 == 0) sAl[qrow] = alpha;
            }

        // rescale O^T acc: lane's q = nt*16 + l15 (wave-local rows; no barrier needed)
        float al0 = sAl[w * 32 + l15], al1 = sAl[w * 32 + 16 + l15];
#pragma unroll
        for (int dt = 0; dt < 8; ++dt)
#pragma unroll
            for (int r = 0; r < 4; ++r) { oc[dt][0][r] *= al0; oc[dt][1][r] *= al1; }

        // O^T += V^T P^T   (A = V^T[d][k], B[k][q] = P[q][k])
#pragma unroll
        for (int ks = 0; ks < 4; ++ks) {
            bf16x8 vf[8], pf[2];
#pragma unroll
            for (int dt = 0; dt < 8; ++dt) {
                int row = dt * 16 + l15;
                int sl = (ks * 4 + quad) ^ (row & 15);
                vf[dt] = *(const bf16x8*)&sV[row * 128 + sl * 8];
            }
#pragma unroll
            for (int nt = 0; nt < 2; ++nt)
                pf[nt] = *(const bf16x8*)&sP[(size_t)(w * 32 + nt * 16 + l15) * 136
                                             + ks * 32 + quad * 8];
#pragma unroll
            for (int dt = 0; dt < 8; ++dt)
#pragma unroll
                for (int nt = 0; nt < 2; ++nt)
                    oc[dt][nt] = __builtin_amdgcn_mfma_f32_16x16x32_bf16(
                        vf[dt], pf[nt], oc[dt][nt], 0, 0, 0);
        }
        __syncthreads();
    }

    // redistribute l via LDS (wave-local rows), write O[q][h*128+d] bf16
#pragma unroll
    for (int mt = 0; mt < 2; ++mt)
#pragma unroll
        for (int r = 0; r < 4; ++r)
            if (l15 == 0) sAl[w * 32 + mt * 16 + quad * 4 + r] = l_r[mt][r];
    float il[2];
    il[0] = 1.f / sAl[w * 32 + l15];
    il[1] = 1.f / sAl[w * 32 + 16 + l15];
#pragma unroll
    for (int nt = 0; nt < 2; ++nt)
#pragma unroll
        for (int dt = 0; dt < 8; ++dt) {
            union { u16 u[4]; uint2 v; } pk;
#pragma unroll
            for (int r = 0; r < 4; ++r) pk.u[r] = f2bf(oc[dt][nt][r] * il[nt]);
            *(uint2*)(O + (size_t)(q0 + w * 32 + nt * 16 + l15) * HIDDEN
                        + h * HD + dt * 16 + quad * 4) = pk.v;
        }
}

// ---------------- host ----------------
extern "C" void kernel_launch(void* const* d_in, const int* in_sizes, int n_in,
                              void* d_out, int out_size, void* d_ws, size_t ws_size,
                              hipStream_t stream) {
    const float* hs = (const float*)d_in[0];
    const int* pos  = (const int*)d_in[1];
    const float* wq = (const float*)d_in[2];
    const float* wk = (const float*)d_in[3];
    const float* wv = (const float*)d_in[4];
    const float* wo = (const float*)d_in[5];
    float* out = (float*)d_out;

    u16* ws    = (u16*)d_ws;
    u16* hid16 = ws;                                     // 8M
    u16* wq16  = hid16 + (size_t)S_LEN * HIDDEN;         // 16M
    u16* wk16  = wq16 + (size_t)HIDDEN * HIDDEN;         // 4M
    u16* wv16  = wk16 + (size_t)NKV * HD * HIDDEN;       // 4M
    u16* wo16  = wv16 + (size_t)NKV * HD * HIDDEN;       // 16M
    u16* qb    = wo16 + (size_t)HIDDEN * HIDDEN;         // 8M
    u16* kb    = qb + (size_t)S_LEN * HIDDEN;            // 2M
    u16* vb    = kb + (size_t)S_LEN * NKV * HD;          // 2M
    u16* vt    = vb + (size_t)S_LEN * NKV * HD;          // 2M
    u16* at    = vt + (size_t)S_LEN * NKV * HD;          // 8M

    dim3 blk(256);
    auto cvt = [&](const float* s, u16* d, size_t n) {
        int n4 = (int)(n / 4);
        cvt_bf16<<<dim3((n4 + 255) / 256), blk, 0, stream>>>(s, d, n4);
    };
    cvt(hs, hid16, (size_t)S_LEN * HIDDEN);
    cvt(wq, wq16, (size_t)HIDDEN * HIDDEN);
    cvt(wk, wk16, (size_t)NKV * HD * HIDDEN);
    cvt(wv, wv16, (size_t)NKV * HD * HIDDEN);
    cvt(wo, wo16, (size_t)HIDDEN * HIDDEN);

    gemm_bt<true><<<dim3(HIDDEN / 128, S_LEN / 128), blk, 0, stream>>>(
        hid16, wq16, (void*)qb, S_LEN, HIDDEN, HIDDEN);
    gemm_bt<true><<<dim3(NKV * HD / 128, S_LEN / 128), blk, 0, stream>>>(
        hid16, wk16, (void*)kb, S_LEN, NKV * HD, HIDDEN);
    gemm_bt<true><<<dim3(NKV * HD / 128, S_LEN / 128), blk, 0, stream>>>(
        hid16, wv16, (void*)vb, S_LEN, NKV * HD, HIDDEN);

    DTab tab;
    for (int i = 0; i < 64; ++i) tab.f[i] = pow(500000.0, -(double)i / 64.0);
    rope_k<<<dim3(S_LEN * NH * 64 / 256), blk, 0, stream>>>(qb, pos, 5, S_LEN * NH * 64, tab);
    rope_k<<<dim3(S_LEN * NKV * 64 / 256), blk, 0, stream>>>(kb, pos, 3, S_LEN * NKV * 64, tab);

    transpose_v<<<dim3(S_LEN / 32, HD / 32, NKV), blk, 0, stream>>>(vb, vt);

    attn_kernel<<<dim3(S_LEN / 128, NH), blk, 0, stream>>>(qb, kb, vt, at);

    gemm_bt<false><<<dim3(HIDDEN / 128, S_LEN / 128), blk, 0, stream>>>(
        at, wo16, (void*)out, S_LEN, HIDDEN, HIDDEN);
}

// Round 2
// 696.232 us; speedup vs baseline: 1.0013x; 1.0013x over previous
//
#include <hip/hip_runtime.h>
#include <stdint.h>
#include <cmath>

typedef unsigned short u16;
typedef unsigned int u32;
typedef __attribute__((ext_vector_type(8))) __bf16 bf16x8;
typedef __attribute__((ext_vector_type(4))) float f32x4;

#define HIDDEN 4096
#define NH 32
#define NKV 8
#define HD 128
#define S_LEN 2048

__device__ __forceinline__ u16 f2bf(float f) {
    u32 x = __float_as_uint(f);
    x += 0x7fff + ((x >> 16) & 1);   // RNE
    return (u16)(x >> 16);
}
__device__ __forceinline__ float bf2f(u16 u) {
    return __uint_as_float(((u32)u) << 16);
}
__device__ __forceinline__ float fexp2(float x) {
#if __has_builtin(__builtin_amdgcn_exp2f)
    return __builtin_amdgcn_exp2f(x);
#else
    return __expf(x * 0.6931471805599453f);
#endif
}

typedef __attribute__((address_space(1))) const void gv_t;
typedef __attribute__((address_space(3))) void lv_t;
__device__ __forceinline__ void async16(const u16* g, u16* s) {
    __builtin_amdgcn_global_load_lds((gv_t*)g, (lv_t*)s, 16, 0, 0);
}

// ---------------- f32 -> bf16 convert ----------------
__global__ void cvt_bf16(const float* __restrict__ src, u16* __restrict__ dst, int n4) {
    int i = blockIdx.x * 256 + threadIdx.x;
    if (i < n4) {
        float4 v = ((const float4*)src)[i];
        union { u16 u[4]; uint2 w; } pk;
        pk.u[0] = f2bf(v.x); pk.u[1] = f2bf(v.y);
        pk.u[2] = f2bf(v.z); pk.u[3] = f2bf(v.w);
        ((uint2*)dst)[i] = pk.w;
    }
}

// ---------------- bf16 GEMM: C[M,N] = A[M,K] * B[N,K]^T ----------------
template <bool OUT_BF16>
__global__ __launch_bounds__(256, 2) void gemm_bt(
    const u16* __restrict__ A, const u16* __restrict__ B, void* __restrict__ Cv,
    int M, int N, int K)
{
    __shared__ u16 sA[128 * 64];
    __shared__ u16 sB[128 * 64];
    const int tid = threadIdx.x;
    const int w = tid >> 6, lane = tid & 63;
    const int l15 = lane & 15, quad = lane >> 4;
    const int m0 = blockIdx.y * 128, n0 = blockIdx.x * 128;
    const int wm = w & 1, wn = w >> 1;

    f32x4 acc[4][4];
#pragma unroll
    for (int mi = 0; mi < 4; ++mi)
#pragma unroll
        for (int ni = 0; ni < 4; ++ni)
#pragma unroll
            for (int r = 0; r < 4; ++r) acc[mi][ni][r] = 0.f;

    for (int kt = 0; kt < K; kt += 64) {
#pragma unroll
        for (int i = 0; i < 4; ++i) {           // A tile: 1024 chunks of 16B
            int c = (i * 4 + w) * 64 + lane;
            int r = c >> 3, sl = c & 7, g = sl ^ (r & 7);
            async16(A + (size_t)(m0 + r) * K + kt + g * 8, &sA[c * 8]);
        }
#pragma unroll
        for (int i = 0; i < 4; ++i) {           // B tile
            int c = (i * 4 + w) * 64 + lane;
            int r = c >> 3, sl = c & 7, g = sl ^ (r & 7);
            async16(B + (size_t)(n0 + r) * K + kt + g * 8, &sB[c * 8]);
        }
        __syncthreads();
#pragma unroll
        for (int ks = 0; ks < 2; ++ks) {
            bf16x8 af[4], bf[4];
#pragma unroll
            for (int t = 0; t < 4; ++t) {
                int row = wm * 64 + t * 16 + l15;
                int sl = (ks * 4 + quad) ^ (row & 7);
                af[t] = *(const bf16x8*)&sA[row * 64 + sl * 8];
            }
#pragma unroll
            for (int t = 0; t < 4; ++t) {
                int row = wn * 64 + t * 16 + l15;
                int sl = (ks * 4 + quad) ^ (row & 7);
                bf[t] = *(const bf16x8*)&sB[row * 64 + sl * 8];
            }
#pragma unroll
            for (int mi = 0; mi < 4; ++mi)
#pragma unroll
                for (int ni = 0; ni < 4; ++ni)
                    acc[mi][ni] = __builtin_amdgcn_mfma_f32_16x16x32_bf16(
                        af[mi], bf[ni], acc[mi][ni], 0, 0, 0);
        }
        __syncthreads();
    }
#pragma unroll
    for (int mi = 0; mi < 4; ++mi) {
        int row = m0 + wm * 64 + mi * 16 + quad * 4;
#pragma unroll
        for (int ni = 0; ni < 4; ++ni) {
            int col = n0 + wn * 64 + ni * 16 + l15;
#pragma unroll
            for (int r = 0; r < 4; ++r) {
                if (OUT_BF16)
                    ((u16*)Cv)[(size_t)(row + r) * N + col] = f2bf(acc[mi][ni][r]);
                else
                    ((float*)Cv)[(size_t)(row + r) * N + col] = acc[mi][ni][r];
            }
        }
    }
}

// ---------------- RoPE (in-place, bf16), f64 phase; oscale folds sm_scale*log2e for Q ----
struct DTab { double f[64]; };
__global__ void rope_k(u16* __restrict__ buf, const int* __restrict__ pos,
                       int logH, int total, float oscale, DTab tab)
{
    int idx = blockIdx.x * 256 + threadIdx.x;
    if (idx >= total) return;
    int d = idx & 63;
    int rest = idx >> 6;           // = s*H + h
    int s = rest >> logH;
    double fr = (double)pos[s] * tab.f[d];
    double sd, cd;
    sincos(fr, &sd, &cd);
    float c = (float)cd * oscale, sn = (float)sd * oscale;
    u16* p = buf + (size_t)rest * HD + d;
    float x1 = bf2f(p[0]), x2 = bf2f(p[64]);
    p[0]  = f2bf(x1 * c - x2 * sn);
    p[64] = f2bf(x2 * c + x1 * sn);
}

// ---------------- V transpose: [S][8][128] -> [8][128][S] ----------------
__global__ void transpose_v(const u16* __restrict__ v, u16* __restrict__ vt) {
    __shared__ u16 t[32][33];
    int h = blockIdx.z;
    int s0 = blockIdx.x * 32, d0 = blockIdx.y * 32;
    int tx = threadIdx.x & 31, ty = threadIdx.x >> 5;
    for (int i = ty; i < 32; i += 8)
        t[i][tx] = v[((size_t)(s0 + i) * NKV + h) * HD + d0 + tx];
    __syncthreads();
    for (int i = ty; i < 32; i += 8)
        vt[((size_t)h * HD + d0 + i) * S_LEN + s0 + tx] = t[tx][i];
}

// ---------------- flash attention (non-causal, GQA 4:1) ----------------
// block = (head, q-tile 128); wave w owns q rows [w*32, w*32+32).
// Q is pre-scaled by sm_scale*log2e (softmax in exp2 domain).
// sP aliased onto sK (chunk-major [k>>3][q][8]) -> LDS 64.5 KB -> 2 blocks/CU.
__global__ __launch_bounds__(256, 2) void attn_kernel(
    const u16* __restrict__ Q, const u16* __restrict__ Kb,
    const u16* __restrict__ Vt, u16* __restrict__ O)
{
    __shared__ u16 sK[128 * 128];          // phase 1: K tile; phase 2: P (chunk-major)
    __shared__ u16 sV[128 * 128];
    __shared__ float sAl[128];
    u16* const sP = sK;

    const int tid = threadIdx.x;
    const int w = tid >> 6, lane = tid & 63;
    const int l15 = lane & 15, quad = lane >> 4;
    const int h = blockIdx.y, q0 = blockIdx.x * 128;
    const int hk = h >> 2;

    // preload Q fragments (A-operand: m=lane&15, k=quad*8+j); Q already scaled
    bf16x8 qf[2][4];
#pragma unroll
    for (int mt = 0; mt < 2; ++mt)
#pragma unroll
        for (int ks = 0; ks < 4; ++ks)
            qf[mt][ks] = *(const bf16x8*)(Q + (size_t)(q0 + w * 32 + mt * 16 + l15) * HIDDEN
                                           + h * HD + ks * 32 + quad * 8);

    f32x4 oc[8][2];
#pragma unroll
    for (int dt = 0; dt < 8; ++dt)
#pragma unroll
        for (int nt = 0; nt < 2; ++nt)
#pragma unroll
            for (int r = 0; r < 4; ++r) oc[dt][nt][r] = 0.f;
    float m_r[2][4], l_r[2][4];
#pragma unroll
    for (int mt = 0; mt < 2; ++mt)
#pragma unroll
        for (int r = 0; r < 4; ++r) { m_r[mt][r] = -1e30f; l_r[mt][r] = 0.f; }

    for (int kb = 0; kb < 16; ++kb) {
        const int k0 = kb * 128;
#pragma unroll
        for (int i = 0; i < 8; ++i) {   // K tile [kidx][d]
            int c = (i * 4 + w) * 64 + lane;
            int r = c >> 4, sl = c & 15, g = sl ^ (r & 15);
            async16(Kb + (size_t)(k0 + r) * (NKV * HD) + hk * HD + g * 8, &sK[c * 8]);
        }
#pragma unroll
        for (int i = 0; i < 8; ++i) {   // V^T tile [d][kidx]
            int c = (i * 4 + w) * 64 + lane;
            int r = c >> 4, sl = c & 15, g = sl ^ (r & 15);
            async16(Vt + (size_t)(hk * HD + r) * S_LEN + k0 + g * 8, &sV[c * 8]);
        }
        __syncthreads();

        // S = Q K^T  (result already in exp2 domain units)
        f32x4 sa[2][8];
#pragma unroll
        for (int mt = 0; mt < 2; ++mt)
#pragma unroll
            for (int nt = 0; nt < 8; ++nt)
#pragma unroll
                for (int r = 0; r < 4; ++r) sa[mt][nt][r] = 0.f;
#pragma unroll
        for (int ks = 0; ks < 4; ++ks) {
            bf16x8 kf[8];
#pragma unroll
            for (int nt = 0; nt < 8; ++nt) {
                int row = nt * 16 + l15;
                int sl = (ks * 4 + quad) ^ (row & 15);
                kf[nt] = *(const bf16x8*)&sK[row * 128 + sl * 8];
            }
#pragma unroll
            for (int mt = 0; mt < 2; ++mt)
#pragma unroll
                for (int nt = 0; nt < 8; ++nt)
                    sa[mt][nt] = __builtin_amdgcn_mfma_f32_16x16x32_bf16(
                        qf[mt][ks], kf[nt], sa[mt][nt], 0, 0, 0);
        }
        __syncthreads();   // all waves done reading sK; safe to write P there

        // online softmax (rows wave-local): p = 2^(s - m)
#pragma unroll
        for (int mt = 0; mt < 2; ++mt)
#pragma unroll
            for (int r = 0; r < 4; ++r) {
                float mx = -1e30f;
#pragma unroll
                for (int nt = 0; nt < 8; ++nt) mx = fmaxf(mx, sa[mt][nt][r]);
#pragma unroll
                for (int off = 1; off < 16; off <<= 1)
                    mx = fmaxf(mx, __shfl_xor(mx, off, 16));
                float mnew = fmaxf(m_r[mt][r], mx);
                float alpha = fexp2(m_r[mt][r] - mnew);
                m_r[mt][r] = mnew;
                float rs = 0.f;
                int qrow = w * 32 + mt * 16 + quad * 4 + r;
                // chunk-major P: elem (q,k) at (k>>3)*1024 + q*8 + (k&7)
                u16* pb = sP + (l15 >> 3) * 1024 + qrow * 8 + (l15 & 7);
#pragma unroll
                for (int nt = 0; nt < 8; ++nt) {
                    float p = fexp2(sa[mt][nt][r] - mnew);
                    rs += p;
                    pb[nt * 2048] = f2bf(p);
                }
#pragma unroll
                for (int off = 1; off < 16; off <<= 1)
                    rs += __shfl_xor(rs, off, 16);
                l_r[mt][r] = l_r[mt][r] * alpha + rs;
                if (l15 == 0) sAl[qrow] = alpha;
            }

        // rescale O^T acc (wave-local rows; no barrier needed)
        float al0 = sAl[w * 32 + l15], al1 = sAl[w * 32 + 16 + l15];
#pragma unroll
        for (int dt = 0; dt < 8; ++dt)
#pragma unroll
            for (int r = 0; r < 4; ++r) { oc[dt][0][r] *= al0; oc[dt][1][r] *= al1; }

        // O^T += V^T P^T
#pragma unroll
        for (int ks = 0; ks < 4; ++ks) {
            bf16x8 vf[8], pf[2];
#pragma unroll
            for (int dt = 0; dt < 8; ++dt) {
                int row = dt * 16 + l15;
                int sl = (ks * 4 + quad) ^ (row & 15);
                vf[dt] = *(const bf16x8*)&sV[row * 128 + sl * 8];
            }
#pragma unroll
            for (int nt = 0; nt < 2; ++nt)
                pf[nt] = *(const bf16x8*)&sP[((ks * 4 + quad) * 128
                                              + w * 32 + nt * 16 + l15) * 8];
#pragma unroll
            for (int dt = 0; dt < 8; ++dt)
#pragma unroll
                for (int nt = 0; nt < 2; ++nt)
                    oc[dt][nt] = __builtin_amdgcn_mfma_f32_16x16x32_bf16(
                        vf[dt], pf[nt], oc[dt][nt], 0, 0, 0);
        }
        __syncthreads();   // P/V reads done before next staging overwrites
    }

    // final normalize + store O[q][h*128+d] bf16
#pragma unroll
    for (int mt = 0; mt < 2; ++mt)
#pragma unroll
        for (int r = 0; r < 4; ++r)
            if (l15 == 0) sAl[w * 32 + mt * 16 + quad * 4 + r] = l_r[mt][r];
    float il[2];
    il[0] = 1.f / sAl[w * 32 + l15];
    il[1] = 1.f / sAl[w * 32 + 16 + l15];
#pragma unroll
    for (int nt = 0; nt < 2; ++nt)
#pragma unroll
        for (int dt = 0; dt < 8; ++dt) {
            union { u16 u[4]; uint2 v; } pk;
#pragma unroll
            for (int r = 0; r < 4; ++r) pk.u[r] = f2bf(oc[dt][nt][r] * il[nt]);
            *(uint2*)(O + (size_t)(q0 + w * 32 + nt * 16 + l15) * HIDDEN
                        + h * HD + dt * 16 + quad * 4) = pk.v;
        }
}

// ---------------- host ----------------
extern "C" void kernel_launch(void* const* d_in, const int* in_sizes, int n_in,
                              void* d_out, int out_size, void* d_ws, size_t ws_size,
                              hipStream_t stream) {
    const float* hs = (const float*)d_in[0];
    const int* pos  = (const int*)d_in[1];
    const float* wq = (const float*)d_in[2];
    const float* wk = (const float*)d_in[3];
    const float* wv = (const float*)d_in[4];
    const float* wo = (const float*)d_in[5];
    float* out = (float*)d_out;

    u16* ws    = (u16*)d_ws;
    u16* hid16 = ws;
    u16* wq16  = hid16 + (size_t)S_LEN * HIDDEN;
    u16* wk16  = wq16 + (size_t)HIDDEN * HIDDEN;
    u16* wv16  = wk16 + (size_t)NKV * HD * HIDDEN;
    u16* wo16  = wv16 + (size_t)NKV * HD * HIDDEN;
    u16* qb    = wo16 + (size_t)HIDDEN * HIDDEN;
    u16* kb    = qb + (size_t)S_LEN * HIDDEN;
    u16* vb    = kb + (size_t)S_LEN * NKV * HD;
    u16* vt    = vb + (size_t)S_LEN * NKV * HD;
    u16* at    = vt + (size_t)S_LEN * NKV * HD;

    dim3 blk(256);
    auto cvt = [&](const float* s, u16* d, size_t n) {
        int n4 = (int)(n / 4);
        cvt_bf16<<<dim3((n4 + 255) / 256), blk, 0, stream>>>(s, d, n4);
    };
    cvt(hs, hid16, (size_t)S_LEN * HIDDEN);
    cvt(wq, wq16, (size_t)HIDDEN * HIDDEN);
    cvt(wk, wk16, (size_t)NKV * HD * HIDDEN);
    cvt(wv, wv16, (size_t)NKV * HD * HIDDEN);
    cvt(wo, wo16, (size_t)HIDDEN * HIDDEN);

    gemm_bt<true><<<dim3(HIDDEN / 128, S_LEN / 128), blk, 0, stream>>>(
        hid16, wq16, (void*)qb, S_LEN, HIDDEN, HIDDEN);
    gemm_bt<true><<<dim3(NKV * HD / 128, S_LEN / 128), blk, 0, stream>>>(
        hid16, wk16, (void*)kb, S_LEN, NKV * HD, HIDDEN);
    gemm_bt<true><<<dim3(NKV * HD / 128, S_LEN / 128), blk, 0, stream>>>(
        hid16, wv16, (void*)vb, S_LEN, NKV * HD, HIDDEN);

    DTab tab;
    for (int i = 0; i < 64; ++i) tab.f[i] = pow(500000.0, -(double)i / 64.0);
    const float qscale = 0.08838834764831845f * 1.4426950408889634f; // sm_scale*log2e
    rope_k<<<dim3(S_LEN * NH * 64 / 256), blk, 0, stream>>>(
        qb, pos, 5, S_LEN * NH * 64, qscale, tab);
    rope_k<<<dim3(S_LEN * NKV * 64 / 256), blk, 0, stream>>>(
        kb, pos, 3, S_LEN * NKV * 64, 1.0f, tab);

    transpose_v<<<dim3(S_LEN / 32, HD / 32, NKV), blk, 0, stream>>>(vb, vt);

    attn_kernel<<<dim3(S_LEN / 128, NH), blk, 0, stream>>>(qb, kb, vt, at);

    gemm_bt<false><<<dim3(HIDDEN / 128, S_LEN / 128), blk, 0, stream>>>(
        at, wo16, (void*)out, S_LEN, HIDDEN, HIDDEN);
}

// Round 3
// 677.807 us; speedup vs baseline: 1.0285x; 1.0272x over previous
//
#include <hip/hip_runtime.h>
#include <stdint.h>
#include <cmath>

typedef unsigned short u16;
typedef unsigned int u32;
typedef __attribute__((ext_vector_type(8))) __bf16 bf16x8;
typedef __attribute__((ext_vector_type(4))) float f32x4;

#define HIDDEN 4096
#define NH 32
#define NKV 8
#define HD 128
#define S_LEN 2048

__device__ __forceinline__ u16 f2bf(float f) {
    u32 x = __float_as_uint(f);
    x += 0x7fff + ((x >> 16) & 1);   // RNE
    return (u16)(x >> 16);
}
__device__ __forceinline__ float bf2f(u16 u) {
    return __uint_as_float(((u32)u) << 16);
}
__device__ __forceinline__ float fexp2(float x) {
#if __has_builtin(__builtin_amdgcn_exp2f)
    return __builtin_amdgcn_exp2f(x);
#else
    return __expf(x * 0.6931471805599453f);
#endif
}

typedef __attribute__((address_space(1))) const void gv_t;
typedef __attribute__((address_space(3))) void lv_t;
__device__ __forceinline__ void async16(const u16* g, u16* s) {
    __builtin_amdgcn_global_load_lds((gv_t*)g, (lv_t*)s, 16, 0, 0);
}

// ---------------- f32 -> bf16 convert ----------------
__global__ void cvt_bf16(const float* __restrict__ src, u16* __restrict__ dst, int n4) {
    int i = blockIdx.x * 256 + threadIdx.x;
    if (i < n4) {
        float4 v = ((const float4*)src)[i];
        union { u16 u[4]; uint2 w; } pk;
        pk.u[0] = f2bf(v.x); pk.u[1] = f2bf(v.y);
        pk.u[2] = f2bf(v.z); pk.u[3] = f2bf(v.w);
        ((uint2*)dst)[i] = pk.w;
    }
}

// ---------------- bf16 GEMM core macro-ish: 128x128 tile, BK=64 ----------------
// (shared by generic O-proj GEMM and the fused QKV GEMM)
#define GEMM_PROLOGUE_AND_MAINLOOP(Aptr, Bptr, Kdim)                                   \
    __shared__ u16 sA[128 * 64];                                                       \
    __shared__ u16 sB[128 * 64];                                                       \
    const int tid = threadIdx.x;                                                       \
    const int w = tid >> 6, lane = tid & 63;                                           \
    const int l15 = lane & 15, quad = lane >> 4;                                       \
    const int m0 = blockIdx.y * 128, n0 = blockIdx.x * 128;                            \
    const int wm = w & 1, wn = w >> 1;                                                 \
    f32x4 acc[4][4];                                                                   \
    _Pragma("unroll") for (int mi = 0; mi < 4; ++mi)                                   \
    _Pragma("unroll") for (int ni = 0; ni < 4; ++ni)                                   \
    _Pragma("unroll") for (int r = 0; r < 4; ++r) acc[mi][ni][r] = 0.f;                \
    for (int kt = 0; kt < (Kdim); kt += 64) {                                          \
        _Pragma("unroll") for (int i = 0; i < 4; ++i) {                                \
            int c = (i * 4 + w) * 64 + lane;                                           \
            int r = c >> 3, sl = c & 7, g = sl ^ (r & 7);                              \
            async16((Aptr) + (size_t)(m0 + r) * (Kdim) + kt + g * 8, &sA[c * 8]);      \
        }                                                                              \
        _Pragma("unroll") for (int i = 0; i < 4; ++i) {                                \
            int c = (i * 4 + w) * 64 + lane;                                           \
            int r = c >> 3, sl = c & 7, g = sl ^ (r & 7);                              \
            async16((Bptr) + (size_t)(n0 + r) * (Kdim) + kt + g * 8, &sB[c * 8]);      \
        }                                                                              \
        __syncthreads();                                                               \
        _Pragma("unroll") for (int ks = 0; ks < 2; ++ks) {                             \
            bf16x8 af[4], bf[4];                                                       \
            _Pragma("unroll") for (int t = 0; t < 4; ++t) {                            \
                int row = wm * 64 + t * 16 + l15;                                      \
                int sl = (ks * 4 + quad) ^ (row & 7);                                  \
                af[t] = *(const bf16x8*)&sA[row * 64 + sl * 8];                        \
            }                                                                          \
            _Pragma("unroll") for (int t = 0; t < 4; ++t) {                            \
                int row = wn * 64 + t * 16 + l15;                                      \
                int sl = (ks * 4 + quad) ^ (row & 7);                                  \
                bf[t] = *(const bf16x8*)&sB[row * 64 + sl * 8];                        \
            }                                                                          \
            _Pragma("unroll") for (int mi = 0; mi < 4; ++mi)                           \
            _Pragma("unroll") for (int ni = 0; ni < 4; ++ni)                           \
                acc[mi][ni] = __builtin_amdgcn_mfma_f32_16x16x32_bf16(                 \
                    af[mi], bf[ni], acc[mi][ni], 0, 0, 0);                             \
        }                                                                              \
        __syncthreads();                                                               \
    }

// Generic: C[M,N] = A[M,K] * B[N,K]^T, f32 out (O-projection)
__global__ __launch_bounds__(256, 2) void gemm_bt_f32(
    const u16* __restrict__ A, const u16* __restrict__ B, float* __restrict__ C,
    int N, int K)
{
    GEMM_PROLOGUE_AND_MAINLOOP(A, B, K)
#pragma unroll
    for (int mi = 0; mi < 4; ++mi) {
        int row = m0 + wm * 64 + mi * 16 + quad * 4;
#pragma unroll
        for (int ni = 0; ni < 4; ++ni) {
            int col = n0 + wn * 64 + ni * 16 + l15;
#pragma unroll
            for (int r = 0; r < 4; ++r)
                C[(size_t)(row + r) * N + col] = acc[mi][ni][r];
        }
    }
}

// Fused QKV: A=[2048,4096] hs, B=[6144,4096] (wq|wk|wv rows), routes output:
//   n<4096 -> qb[s][n] ; 4096<=n<5120 -> kbuf[s][n-4096] ; n>=5120 -> vt[c][s] (transposed)
__global__ __launch_bounds__(256, 2) void gemm_qkv(
    const u16* __restrict__ A, const u16* __restrict__ B,
    u16* __restrict__ qb, u16* __restrict__ kbuf, u16* __restrict__ vt)
{
    GEMM_PROLOGUE_AND_MAINLOOP(A, B, HIDDEN)
    if (n0 < 4096 + 1024) {   // q or k path: plain row-major bf16 write
        u16* outp; int ldo, cb;
        if (n0 < 4096) { outp = qb; ldo = HIDDEN; cb = n0; }
        else           { outp = kbuf; ldo = NKV * HD; cb = n0 - 4096; }
#pragma unroll
        for (int mi = 0; mi < 4; ++mi) {
            int row = m0 + wm * 64 + mi * 16 + quad * 4;
#pragma unroll
            for (int ni = 0; ni < 4; ++ni) {
                int col = cb + wn * 64 + ni * 16 + l15;
#pragma unroll
                for (int r = 0; r < 4; ++r)
                    outp[(size_t)(row + r) * ldo + col] = f2bf(acc[mi][ni][r]);
            }
        }
    } else {                  // v path: write transposed vt[c][s], 4 s-consecutive per lane
        int cb = n0 - (4096 + 1024);
#pragma unroll
        for (int mi = 0; mi < 4; ++mi) {
            int row = m0 + wm * 64 + mi * 16 + quad * 4;
#pragma unroll
            for (int ni = 0; ni < 4; ++ni) {
                int c = cb + wn * 64 + ni * 16 + l15;
                union { u16 u[4]; uint2 v; } pk;
#pragma unroll
                for (int r = 0; r < 4; ++r) pk.u[r] = f2bf(acc[mi][ni][r]);
                *(uint2*)&vt[(size_t)c * S_LEN + row] = pk.v;
            }
        }
    }
}

// ---------------- RoPE (in-place, bf16), f64 phase; oscale folds sm_scale*log2e for Q ----
struct DTab { double f[64]; };
__global__ void rope_k(u16* __restrict__ buf, const int* __restrict__ pos,
                       int logH, int total, float oscale, DTab tab)
{
    int idx = blockIdx.x * 256 + threadIdx.x;
    if (idx >= total) return;
    int d = idx & 63;
    int rest = idx >> 6;           // = s*H + h
    int s = rest >> logH;
    double fr = (double)pos[s] * tab.f[d];
    double sd, cd;
    sincos(fr, &sd, &cd);
    float c = (float)cd * oscale, sn = (float)sd * oscale;
    u16* p = buf + (size_t)rest * HD + d;
    float x1 = bf2f(p[0]), x2 = bf2f(p[64]);
    p[0]  = f2bf(x1 * c - x2 * sn);
    p[64] = f2bf(x2 * c + x1 * sn);
}

// ---------------- flash attention: barrier-free, direct L2->VGPR K/V frags ----------
// block = (head, q-tile 128); wave w owns q rows [w*32,w*32+32) -- fully wave-local.
// Q pre-scaled by sm_scale*log2e (exp2-domain softmax). P round-trips through
// wave-private LDS (chunk-major, 264-u16 chunk stride = 16B aligned, conflict-light).
// K frags read from kb[s][d] (16B/lane contiguous); V frags from vt[d][s].
__global__ __launch_bounds__(256, 2) void attn_kernel(
    const u16* __restrict__ Q, const u16* __restrict__ Kb,
    const u16* __restrict__ Vt, u16* __restrict__ O)
{
    __shared__ __align__(16) u16 sP[4][16 * 264];   // per-wave private
    __shared__ float sAl[4][32];

    const int tid = threadIdx.x;
    const int w = tid >> 6, lane = tid & 63;
    const int l15 = lane & 15, quad = lane >> 4;
    const int h = blockIdx.y, q0 = blockIdx.x * 128;
    const int hk = h >> 2;
    u16* const sPw = sP[w];

    // Q frags (A-operand: m=lane&15, k=quad*8+j); Q already scaled
    bf16x8 qf[2][4];
#pragma unroll
    for (int mt = 0; mt < 2; ++mt)
#pragma unroll
        for (int ks = 0; ks < 4; ++ks)
            qf[mt][ks] = *(const bf16x8*)(Q + (size_t)(q0 + w * 32 + mt * 16 + l15) * HIDDEN
                                           + h * HD + ks * 32 + quad * 8);

    f32x4 oc[8][2];
#pragma unroll
    for (int dt = 0; dt < 8; ++dt)
#pragma unroll
        for (int nt = 0; nt < 2; ++nt)
#pragma unroll
            for (int r = 0; r < 4; ++r) oc[dt][nt][r] = 0.f;
    float m_r[2][4], l_r[2][4];
#pragma unroll
    for (int mt = 0; mt < 2; ++mt)
#pragma unroll
        for (int r = 0; r < 4; ++r) { m_r[mt][r] = -1e30f; l_r[mt][r] = 0.f; }

    // lane-constant base pointers
    const u16* kb_lane = Kb + hk * HD + quad * 8;                       // + s*1024 + ks*32
    const u16* vt_lane = Vt + (size_t)(hk * HD + l15) * S_LEN + quad * 8; // + dt*16*2048 + k

    for (int kbi = 0; kbi < 16; ++kbi) {
        const int k0 = kbi * 128;

        // ---- S = Q K^T : K frags straight from L2 ----
        f32x4 sa[2][8];
#pragma unroll
        for (int mt = 0; mt < 2; ++mt)
#pragma unroll
            for (int nt = 0; nt < 8; ++nt)
#pragma unroll
                for (int r = 0; r < 4; ++r) sa[mt][nt][r] = 0.f;
#pragma unroll
        for (int ks = 0; ks < 4; ++ks) {
            bf16x8 kf[8];
#pragma unroll
            for (int nt = 0; nt < 8; ++nt)
                kf[nt] = *(const bf16x8*)(kb_lane
                            + (size_t)(k0 + nt * 16 + l15) * (NKV * HD) + ks * 32);
#pragma unroll
            for (int mt = 0; mt < 2; ++mt)
#pragma unroll
                for (int nt = 0; nt < 8; ++nt)
                    sa[mt][nt] = __builtin_amdgcn_mfma_f32_16x16x32_bf16(
                        qf[mt][ks], kf[nt], sa[mt][nt], 0, 0, 0);
        }

        // ---- online softmax (wave-local rows): p = 2^(s - m) ----
#pragma unroll
        for (int mt = 0; mt < 2; ++mt)
#pragma unroll
            for (int r = 0; r < 4; ++r) {
                float mx = -1e30f;
#pragma unroll
                for (int nt = 0; nt < 8; ++nt) mx = fmaxf(mx, sa[mt][nt][r]);
#pragma unroll
                for (int off = 1; off < 16; off <<= 1)
                    mx = fmaxf(mx, __shfl_xor(mx, off, 16));
                float mnew = fmaxf(m_r[mt][r], mx);
                float alpha = fexp2(m_r[mt][r] - mnew);
                m_r[mt][r] = mnew;
                int ql = mt * 16 + quad * 4 + r;      // wave-local q row
                // chunk-major P: (q,k) at (k>>3)*264 + q*8 + (k&7); k = nt*16+l15
                u16* pb = sPw + (l15 >> 3) * 264 + ql * 8 + (l15 & 7);
                float rs = 0.f;
#pragma unroll
                for (int nt = 0; nt < 8; ++nt) {
                    float p = fexp2(sa[mt][nt][r] - mnew);
                    rs += p;
                    pb[nt * 528] = f2bf(p);
                }
#pragma unroll
                for (int off = 1; off < 16; off <<= 1)
                    rs += __shfl_xor(rs, off, 16);
                l_r[mt][r] = l_r[mt][r] * alpha + rs;
                if (l15 == 0) sAl[w][ql] = alpha;
            }

        // ---- rescale O^T acc ----
        float al0 = sAl[w][l15], al1 = sAl[w][16 + l15];
#pragma unroll
        for (int dt = 0; dt < 8; ++dt)
#pragma unroll
            for (int r = 0; r < 4; ++r) { oc[dt][0][r] *= al0; oc[dt][1][r] *= al1; }

        // ---- O^T += V^T P^T : V frags straight from L2, P from wave-private LDS ----
#pragma unroll
        for (int ks = 0; ks < 4; ++ks) {
            bf16x8 vf[8], pf[2];
#pragma unroll
            for (int dt = 0; dt < 8; ++dt)
                vf[dt] = *(const bf16x8*)(vt_lane + (size_t)dt * 16 * S_LEN + k0 + ks * 32);
#pragma unroll
            for (int nt = 0; nt < 2; ++nt)
                pf[nt] = *(const bf16x8*)&sPw[(ks * 4 + quad) * 264 + (nt * 16 + l15) * 8];
#pragma unroll
            for (int dt = 0; dt < 8; ++dt)
#pragma unroll
                for (int nt = 0; nt < 2; ++nt)
                    oc[dt][nt] = __builtin_amdgcn_mfma_f32_16x16x32_bf16(
                        vf[dt], pf[nt], oc[dt][nt], 0, 0, 0);
        }
    }

    // ---- finalize: normalize, store O[q][h*128+d] bf16 ----
#pragma unroll
    for (int mt = 0; mt < 2; ++mt)
#pragma unroll
        for (int r = 0; r < 4; ++r)
            if (l15 == 0) sAl[w][mt * 16 + quad * 4 + r] = l_r[mt][r];
    float il[2];
    il[0] = 1.f / sAl[w][l15];
    il[1] = 1.f / sAl[w][16 + l15];
#pragma unroll
    for (int nt = 0; nt < 2; ++nt)
#pragma unroll
        for (int dt = 0; dt < 8; ++dt) {
            union { u16 u[4]; uint2 v; } pk;
#pragma unroll
            for (int r = 0; r < 4; ++r) pk.u[r] = f2bf(oc[dt][nt][r] * il[nt]);
            *(uint2*)(O + (size_t)(q0 + w * 32 + nt * 16 + l15) * HIDDEN
                        + h * HD + dt * 16 + quad * 4) = pk.v;
        }
}

// ---------------- host ----------------
extern "C" void kernel_launch(void* const* d_in, const int* in_sizes, int n_in,
                              void* d_out, int out_size, void* d_ws, size_t ws_size,
                              hipStream_t stream) {
    const float* hs = (const float*)d_in[0];
    const int* pos  = (const int*)d_in[1];
    const float* wq = (const float*)d_in[2];
    const float* wk = (const float*)d_in[3];
    const float* wv = (const float*)d_in[4];
    const float* wo = (const float*)d_in[5];
    float* out = (float*)d_out;

    u16* ws    = (u16*)d_ws;
    u16* hid16 = ws;
    u16* wq16  = hid16 + (size_t)S_LEN * HIDDEN;          // wq|wk|wv contiguous = wqkv
    u16* wk16  = wq16 + (size_t)HIDDEN * HIDDEN;
    u16* wv16  = wk16 + (size_t)NKV * HD * HIDDEN;
    u16* wo16  = wv16 + (size_t)NKV * HD * HIDDEN;
    u16* qb    = wo16 + (size_t)HIDDEN * HIDDEN;
    u16* kb    = qb + (size_t)S_LEN * HIDDEN;
    u16* vt    = kb + (size_t)S_LEN * NKV * HD;
    u16* at    = vt + (size_t)S_LEN * NKV * HD;

    dim3 blk(256);
    auto cvt = [&](const float* s, u16* d, size_t n) {
        int n4 = (int)(n / 4);
        cvt_bf16<<<dim3((n4 + 255) / 256), blk, 0, stream>>>(s, d, n4);
    };
    cvt(hs, hid16, (size_t)S_LEN * HIDDEN);
    cvt(wq, wq16, (size_t)HIDDEN * HIDDEN);
    cvt(wk, wk16, (size_t)NKV * HD * HIDDEN);
    cvt(wv, wv16, (size_t)NKV * HD * HIDDEN);
    cvt(wo, wo16, (size_t)HIDDEN * HIDDEN);

    // fused QKV projection (V written transposed)
    gemm_qkv<<<dim3((HIDDEN + 2 * NKV * HD) / 128, S_LEN / 128), blk, 0, stream>>>(
        hid16, wq16, qb, kb, vt);

    DTab tab;
    for (int i = 0; i < 64; ++i) tab.f[i] = pow(500000.0, -(double)i / 64.0);
    const float qscale = 0.08838834764831845f * 1.4426950408889634f; // sm_scale*log2e
    rope_k<<<dim3(S_LEN * NH * 64 / 256), blk, 0, stream>>>(
        qb, pos, 5, S_LEN * NH * 64, qscale, tab);
    rope_k<<<dim3(S_LEN * NKV * 64 / 256), blk, 0, stream>>>(
        kb, pos, 3, S_LEN * NKV * 64, 1.0f, tab);

    attn_kernel<<<dim3(S_LEN / 128, NH), blk, 0, stream>>>(qb, kb, vt, at);

    gemm_bt_f32<<<dim3(HIDDEN / 128, S_LEN / 128), blk, 0, stream>>>(
        at, wo16, out, HIDDEN, HIDDEN);
}

// Round 5
// 545.277 us; speedup vs baseline: 1.2785x; 1.2431x over previous
//
#include <hip/hip_runtime.h>
#include <stdint.h>
#include <cmath>

typedef unsigned short u16;
typedef unsigned int u32;
typedef __attribute__((ext_vector_type(8))) __bf16 bf16x8;
typedef __attribute__((ext_vector_type(4))) float f32x4;

#define HIDDEN 4096
#define NH 32
#define NKV 8
#define HD 128
#define S_LEN 2048

__device__ __forceinline__ u16 f2bf(float f) {
    u32 x = __float_as_uint(f);
    x += 0x7fff + ((x >> 16) & 1);   // RNE
    return (u16)(x >> 16);
}
__device__ __forceinline__ float bf2f(u16 u) {
    return __uint_as_float(((u32)u) << 16);
}
__device__ __forceinline__ float fexp2(float x) {
#if __has_builtin(__builtin_amdgcn_exp2f)
    return __builtin_amdgcn_exp2f(x);
#else
    return __expf(x * 0.6931471805599453f);
#endif
}

typedef __attribute__((address_space(1))) const void gv_t;
typedef __attribute__((address_space(3))) void lv_t;
__device__ __forceinline__ void async16(const u16* g, u16* s) {
    __builtin_amdgcn_global_load_lds((gv_t*)g, (lv_t*)s, 16, 0, 0);
}

// ---------------- f32 -> bf16 convert ----------------
__global__ void cvt_bf16(const float* __restrict__ src, u16* __restrict__ dst, int n4) {
    int i = blockIdx.x * 256 + threadIdx.x;
    if (i < n4) {
        float4 v = ((const float4*)src)[i];
        union { u16 u[4]; uint2 w; } pk;
        pk.u[0] = f2bf(v.x); pk.u[1] = f2bf(v.y);
        pk.u[2] = f2bf(v.z); pk.u[3] = f2bf(v.w);
        ((uint2*)dst)[i] = pk.w;
    }
}

// ---------------- bf16 GEMM core: 128x128 tile, BK=64 ----------------
#define GEMM_PROLOGUE_AND_MAINLOOP(Aptr, Bptr, Kdim)                                   \
    __shared__ u16 sA[128 * 64];                                                       \
    __shared__ u16 sB[128 * 64];                                                       \
    const int tid = threadIdx.x;                                                       \
    const int w = tid >> 6, lane = tid & 63;                                           \
    const int l15 = lane & 15, quad = lane >> 4;                                       \
    const int m0 = blockIdx.y * 128, n0 = blockIdx.x * 128;                            \
    const int wm = w & 1, wn = w >> 1;                                                 \
    f32x4 acc[4][4];                                                                   \
    _Pragma("unroll") for (int mi = 0; mi < 4; ++mi)                                   \
    _Pragma("unroll") for (int ni = 0; ni < 4; ++ni)                                   \
    _Pragma("unroll") for (int r = 0; r < 4; ++r) acc[mi][ni][r] = 0.f;                \
    for (int kt = 0; kt < (Kdim); kt += 64) {                                          \
        _Pragma("unroll") for (int i = 0; i < 4; ++i) {                                \
            int c = (i * 4 + w) * 64 + lane;                                           \
            int r = c >> 3, sl = c & 7, g = sl ^ (r & 7);                              \
            async16((Aptr) + (size_t)(m0 + r) * (Kdim) + kt + g * 8, &sA[c * 8]);      \
        }                                                                              \
        _Pragma("unroll") for (int i = 0; i < 4; ++i) {                                \
            int c = (i * 4 + w) * 64 + lane;                                           \
            int r = c >> 3, sl = c & 7, g = sl ^ (r & 7);                              \
            async16((Bptr) + (size_t)(n0 + r) * (Kdim) + kt + g * 8, &sB[c * 8]);      \
        }                                                                              \
        __syncthreads();                                                               \
        _Pragma("unroll") for (int ks = 0; ks < 2; ++ks) {                             \
            bf16x8 af[4], bf[4];                                                       \
            _Pragma("unroll") for (int t = 0; t < 4; ++t) {                            \
                int row = wm * 64 + t * 16 + l15;                                      \
                int sl = (ks * 4 + quad) ^ (row & 7);                                  \
                af[t] = *(const bf16x8*)&sA[row * 64 + sl * 8];                        \
            }                                                                          \
            _Pragma("unroll") for (int t = 0; t < 4; ++t) {                            \
                int row = wn * 64 + t * 16 + l15;                                      \
                int sl = (ks * 4 + quad) ^ (row & 7);                                  \
                bf[t] = *(const bf16x8*)&sB[row * 64 + sl * 8];                        \
            }                                                                          \
            _Pragma("unroll") for (int mi = 0; mi < 4; ++mi)                           \
            _Pragma("unroll") for (int ni = 0; ni < 4; ++ni)                           \
                acc[mi][ni] = __builtin_amdgcn_mfma_f32_16x16x32_bf16(                 \
                    af[mi], bf[ni], acc[mi][ni], 0, 0, 0);                             \
        }                                                                              \
        __syncthreads();                                                               \
    }

// Generic: C[M,N] = A[M,K] * B[N,K]^T, f32 out (O-projection)
__global__ __launch_bounds__(256, 2) void gemm_bt_f32(
    const u16* __restrict__ A, const u16* __restrict__ B, float* __restrict__ C,
    int N, int K)
{
    GEMM_PROLOGUE_AND_MAINLOOP(A, B, K)
#pragma unroll
    for (int mi = 0; mi < 4; ++mi) {
        int row = m0 + wm * 64 + mi * 16 + quad * 4;
#pragma unroll
        for (int ni = 0; ni < 4; ++ni) {
            int col = n0 + wn * 64 + ni * 16 + l15;
#pragma unroll
            for (int r = 0; r < 4; ++r)
                C[(size_t)(row + r) * N + col] = acc[mi][ni][r];
        }
    }
}

// Fused QKV: A=[2048,4096] hs, B=[6144,4096] (wq|wk|wv rows), routed output.
__global__ __launch_bounds__(256, 2) void gemm_qkv(
    const u16* __restrict__ A, const u16* __restrict__ B,
    u16* __restrict__ qb, u16* __restrict__ kbuf, u16* __restrict__ vt)
{
    GEMM_PROLOGUE_AND_MAINLOOP(A, B, HIDDEN)
    if (n0 < 4096 + 1024) {   // q or k path: row-major bf16
        u16* outp; int ldo, cb;
        if (n0 < 4096) { outp = qb; ldo = HIDDEN; cb = n0; }
        else           { outp = kbuf; ldo = NKV * HD; cb = n0 - 4096; }
#pragma unroll
        for (int mi = 0; mi < 4; ++mi) {
            int row = m0 + wm * 64 + mi * 16 + quad * 4;
#pragma unroll
            for (int ni = 0; ni < 4; ++ni) {
                int col = cb + wn * 64 + ni * 16 + l15;
#pragma unroll
                for (int r = 0; r < 4; ++r)
                    outp[(size_t)(row + r) * ldo + col] = f2bf(acc[mi][ni][r]);
            }
        }
    } else {                  // v path: transposed vt[c][s]
        int cb = n0 - (4096 + 1024);
#pragma unroll
        for (int mi = 0; mi < 4; ++mi) {
            int row = m0 + wm * 64 + mi * 16 + quad * 4;
#pragma unroll
            for (int ni = 0; ni < 4; ++ni) {
                int c = cb + wn * 64 + ni * 16 + l15;
                union { u16 u[4]; uint2 v; } pk;
#pragma unroll
                for (int r = 0; r < 4; ++r) pk.u[r] = f2bf(acc[mi][ni][r]);
                *(uint2*)&vt[(size_t)c * S_LEN + row] = pk.v;
            }
        }
    }
}

// ---------------- RoPE (in-place, bf16), f64 phase ----------------
struct DTab { double f[64]; };
__global__ void rope_k(u16* __restrict__ buf, const int* __restrict__ pos,
                       int logH, int total, float oscale, DTab tab)
{
    int idx = blockIdx.x * 256 + threadIdx.x;
    if (idx >= total) return;
    int d = idx & 63;
    int rest = idx >> 6;
    int s = rest >> logH;
    double fr = (double)pos[s] * tab.f[d];
    double sd, cd;
    sincos(fr, &sd, &cd);
    float c = (float)cd * oscale, sn = (float)sd * oscale;
    u16* p = buf + (size_t)rest * HD + d;
    float x1 = bf2f(p[0]), x2 = bf2f(p[64]);
    p[0]  = f2bf(x1 * c - x2 * sn);
    p[64] = f2bf(x2 * c + x1 * sn);
}

// ---------------- flash attention: 512 threads, q-tile 256, sequential staging ----
// block = (head, q-tile 256); wave w owns q rows [w*32, w*32+32) -- wave-local softmax.
// Structure = R2's proven stage->barrier->compute->barrier; sP separate (no alias);
// softmax reductions via __shfl_xor (proven). K/V staged once per 8 waves.
__global__ __launch_bounds__(512, 1) void attn_kernel(
    const u16* __restrict__ Q, const u16* __restrict__ Kb,
    const u16* __restrict__ Vt, u16* __restrict__ O)
{
    __shared__ u16 sK[128 * 128];                    // 32 KB
    __shared__ u16 sV[128 * 128];                    // 32 KB
    __shared__ __align__(16) u16 sP[8][16 * 264];    // 66 KB, per-wave private
    __shared__ float sAl[8][32];

    const int tid = threadIdx.x;
    const int w = tid >> 6, lane = tid & 63;
    const int l15 = lane & 15, quad = lane >> 4;
    const int h = blockIdx.y, q0 = blockIdx.x * 256;
    const int hk = h >> 2;
    u16* const sPw = sP[w];

    // Q frags (A-operand: m=lane&15, k=quad*8+j); Q pre-scaled by sm_scale*log2e
    bf16x8 qf[2][4];
#pragma unroll
    for (int mt = 0; mt < 2; ++mt)
#pragma unroll
        for (int ks = 0; ks < 4; ++ks)
            qf[mt][ks] = *(const bf16x8*)(Q + (size_t)(q0 + w * 32 + mt * 16 + l15) * HIDDEN
                                           + h * HD + ks * 32 + quad * 8);

    f32x4 oc[8][2];
#pragma unroll
    for (int dt = 0; dt < 8; ++dt)
#pragma unroll
        for (int nt = 0; nt < 2; ++nt)
#pragma unroll
            for (int r = 0; r < 4; ++r) oc[dt][nt][r] = 0.f;
    float m_r[2][4], l_r[2][4];
#pragma unroll
    for (int mt = 0; mt < 2; ++mt)
#pragma unroll
        for (int r = 0; r < 4; ++r) { m_r[mt][r] = -1e30f; l_r[mt][r] = 0.f; }

    for (int kbi = 0; kbi < 16; ++kbi) {
        const int k0 = kbi * 128;

        // ---- stage K,V tiles: 2048 chunks each, 512 threads x 4; XOR swizzle ----
#pragma unroll
        for (int i = 0; i < 4; ++i) {
            int c = i * 512 + tid;
            int r = c >> 4, sl = c & 15, g = sl ^ (r & 15);
            async16(Kb + (size_t)(k0 + r) * (NKV * HD) + hk * HD + g * 8, &sK[c * 8]);
        }
#pragma unroll
        for (int i = 0; i < 4; ++i) {
            int c = i * 512 + tid;
            int r = c >> 4, sl = c & 15, g = sl ^ (r & 15);
            async16(Vt + (size_t)(hk * HD + r) * S_LEN + k0 + g * 8, &sV[c * 8]);
        }
        __syncthreads();   // staging drained (vmcnt0) + all waves ready

        // ---- S = Q K^T from sK ----
        f32x4 sa[2][8];
#pragma unroll
        for (int mt = 0; mt < 2; ++mt)
#pragma unroll
            for (int nt = 0; nt < 8; ++nt)
#pragma unroll
                for (int r = 0; r < 4; ++r) sa[mt][nt][r] = 0.f;
#pragma unroll
        for (int ks = 0; ks < 4; ++ks) {
            bf16x8 kf[8];
#pragma unroll
            for (int nt = 0; nt < 8; ++nt) {
                int row = nt * 16 + l15;
                int sl = (ks * 4 + quad) ^ (row & 15);
                kf[nt] = *(const bf16x8*)&sK[row * 128 + sl * 8];
            }
#pragma unroll
            for (int mt = 0; mt < 2; ++mt)
#pragma unroll
                for (int nt = 0; nt < 8; ++nt)
                    sa[mt][nt] = __builtin_amdgcn_mfma_f32_16x16x32_bf16(
                        qf[mt][ks], kf[nt], sa[mt][nt], 0, 0, 0);
        }

        // ---- online softmax (shfl_xor reductions, exp2 domain) ----
#pragma unroll
        for (int mt = 0; mt < 2; ++mt)
#pragma unroll
            for (int r = 0; r < 4; ++r) {
                float mx = sa[mt][0][r];
#pragma unroll
                for (int nt = 1; nt < 8; ++nt) mx = fmaxf(mx, sa[mt][nt][r]);
#pragma unroll
                for (int off = 1; off < 16; off <<= 1)
                    mx = fmaxf(mx, __shfl_xor(mx, off, 16));
                float mnew = fmaxf(m_r[mt][r], mx);
                float alpha = fexp2(m_r[mt][r] - mnew);
                m_r[mt][r] = mnew;
                int ql = mt * 16 + quad * 4 + r;
                // chunk-major P: (q,k) at (k>>3)*264 + q*8 + (k&7); k = nt*16+l15
                u16* pb = sPw + (l15 >> 3) * 264 + ql * 8 + (l15 & 7);
                float rs = 0.f;
#pragma unroll
                for (int nt = 0; nt < 8; ++nt) {
                    float p = fexp2(sa[mt][nt][r] - mnew);
                    rs += p;
                    pb[nt * 528] = f2bf(p);
                }
#pragma unroll
                for (int off = 1; off < 16; off <<= 1)
                    rs += __shfl_xor(rs, off, 16);
                l_r[mt][r] = l_r[mt][r] * alpha + rs;
                if (l15 == 0) sAl[w][ql] = alpha;
            }

        // ---- rescale O^T acc (wave-local) ----
        float al0 = sAl[w][l15], al1 = sAl[w][16 + l15];
#pragma unroll
        for (int dt = 0; dt < 8; ++dt)
#pragma unroll
            for (int r = 0; r < 4; ++r) { oc[dt][0][r] *= al0; oc[dt][1][r] *= al1; }

        // ---- O^T += V^T P^T from sV, sPw ----
#pragma unroll
        for (int ks = 0; ks < 4; ++ks) {
            bf16x8 vf[8], pf[2];
#pragma unroll
            for (int dt = 0; dt < 8; ++dt) {
                int row = dt * 16 + l15;
                int sl = (ks * 4 + quad) ^ (row & 15);
                vf[dt] = *(const bf16x8*)&sV[row * 128 + sl * 8];
            }
#pragma unroll
            for (int nt = 0; nt < 2; ++nt)
                pf[nt] = *(const bf16x8*)&sPw[(ks * 4 + quad) * 264 + (nt * 16 + l15) * 8];
#pragma unroll
            for (int dt = 0; dt < 8; ++dt)
#pragma unroll
                for (int nt = 0; nt < 2; ++nt)
                    oc[dt][nt] = __builtin_amdgcn_mfma_f32_16x16x32_bf16(
                        vf[dt], pf[nt], oc[dt][nt], 0, 0, 0);
        }

        __syncthreads();   // all waves done with sK/sV before next staging
    }

    // ---- finalize: normalize, store O[q][h*128+d] bf16 ----
#pragma unroll
    for (int mt = 0; mt < 2; ++mt)
#pragma unroll
        for (int r = 0; r < 4; ++r)
            if (l15 == 0) sAl[w][mt * 16 + quad * 4 + r] = l_r[mt][r];
    float il[2];
    il[0] = 1.f / sAl[w][l15];
    il[1] = 1.f / sAl[w][16 + l15];
#pragma unroll
    for (int nt = 0; nt < 2; ++nt)
#pragma unroll
        for (int dt = 0; dt < 8; ++dt) {
            union { u16 u[4]; uint2 v; } pk;
#pragma unroll
            for (int r = 0; r < 4; ++r) pk.u[r] = f2bf(oc[dt][nt][r] * il[nt]);
            *(uint2*)(O + (size_t)(q0 + w * 32 + nt * 16 + l15) * HIDDEN
                        + h * HD + dt * 16 + quad * 4) = pk.v;
        }
}

// ---------------- host ----------------
extern "C" void kernel_launch(void* const* d_in, const int* in_sizes, int n_in,
                              void* d_out, int out_size, void* d_ws, size_t ws_size,
                              hipStream_t stream) {
    const float* hs = (const float*)d_in[0];
    const int* pos  = (const int*)d_in[1];
    const float* wq = (const float*)d_in[2];
    const float* wk = (const float*)d_in[3];
    const float* wv = (const float*)d_in[4];
    const float* wo = (const float*)d_in[5];
    float* out = (float*)d_out;

    u16* ws    = (u16*)d_ws;
    u16* hid16 = ws;
    u16* wq16  = hid16 + (size_t)S_LEN * HIDDEN;          // wq|wk|wv contiguous
    u16* wk16  = wq16 + (size_t)HIDDEN * HIDDEN;
    u16* wv16  = wk16 + (size_t)NKV * HD * HIDDEN;
    u16* wo16  = wv16 + (size_t)NKV * HD * HIDDEN;
    u16* qb    = wo16 + (size_t)HIDDEN * HIDDEN;
    u16* kb    = qb + (size_t)S_LEN * HIDDEN;
    u16* vt    = kb + (size_t)S_LEN * NKV * HD;
    u16* at    = vt + (size_t)S_LEN * NKV * HD;

    dim3 blk(256);
    auto cvt = [&](const float* s, u16* d, size_t n) {
        int n4 = (int)(n / 4);
        cvt_bf16<<<dim3((n4 + 255) / 256), blk, 0, stream>>>(s, d, n4);
    };
    cvt(hs, hid16, (size_t)S_LEN * HIDDEN);
    cvt(wq, wq16, (size_t)HIDDEN * HIDDEN);
    cvt(wk, wk16, (size_t)NKV * HD * HIDDEN);
    cvt(wv, wv16, (size_t)NKV * HD * HIDDEN);
    cvt(wo, wo16, (size_t)HIDDEN * HIDDEN);

    gemm_qkv<<<dim3((HIDDEN + 2 * NKV * HD) / 128, S_LEN / 128), blk, 0, stream>>>(
        hid16, wq16, qb, kb, vt);

    DTab tab;
    for (int i = 0; i < 64; ++i) tab.f[i] = pow(500000.0, -(double)i / 64.0);
    const float qscale = 0.08838834764831845f * 1.4426950408889634f; // sm_scale*log2e
    rope_k<<<dim3(S_LEN * NH * 64 / 256), blk, 0, stream>>>(
        qb, pos, 5, S_LEN * NH * 64, qscale, tab);
    rope_k<<<dim3(S_LEN * NKV * 64 / 256), blk, 0, stream>>>(
        kb, pos, 3, S_LEN * NKV * 64, 1.0f, tab);

    attn_kernel<<<dim3(S_LEN / 256, NH), dim3(512), 0, stream>>>(qb, kb, vt, at);

    gemm_bt_f32<<<dim3(HIDDEN / 128, S_LEN / 128), blk, 0, stream>>>(
        at, wo16, out, HIDDEN, HIDDEN);
}

// Round 6
// 519.262 us; speedup vs baseline: 1.3425x; 1.0501x over previous
//
#include <hip/hip_runtime.h>
#include <stdint.h>
#include <cmath>

typedef unsigned short u16;
typedef unsigned int u32;
typedef __attribute__((ext_vector_type(8))) __bf16 bf16x8;
typedef __attribute__((ext_vector_type(4))) float f32x4;

#define HIDDEN 4096
#define NH 32
#define NKV 8
#define HD 128
#define S_LEN 2048

__device__ __forceinline__ u16 f2bf(float f) {
    u32 x = __float_as_uint(f);
    x += 0x7fff + ((x >> 16) & 1);   // RNE
    return (u16)(x >> 16);
}
__device__ __forceinline__ float bf2f(u16 u) {
    return __uint_as_float(((u32)u) << 16);
}
__device__ __forceinline__ float fexp2(float x) {
#if __has_builtin(__builtin_amdgcn_exp2f)
    return __builtin_amdgcn_exp2f(x);
#else
    return __expf(x * 0.6931471805599453f);
#endif
}

// DPP rotate within 16-lane row (VALU pipe, not DS). row_ror:N = 0x120+N.
template <int N>
__device__ __forceinline__ float dpp_ror(float v) {
    int i = __builtin_amdgcn_update_dpp(0, __float_as_int(v),
                                        0x120 + N, 0xf, 0xf, true);
    return __int_as_float(i);
}
__device__ __forceinline__ float row_max16(float x) {
    x = fmaxf(x, dpp_ror<1>(x));
    x = fmaxf(x, dpp_ror<2>(x));
    x = fmaxf(x, dpp_ror<4>(x));
    x = fmaxf(x, dpp_ror<8>(x));
    return x;
}
__device__ __forceinline__ float row_sum16(float x) {
    x += dpp_ror<1>(x);
    x += dpp_ror<2>(x);
    x += dpp_ror<4>(x);
    x += dpp_ror<8>(x);
    return x;
}

typedef __attribute__((address_space(1))) const void gv_t;
typedef __attribute__((address_space(3))) void lv_t;
__device__ __forceinline__ void async16(const u16* g, u16* s) {
    __builtin_amdgcn_global_load_lds((gv_t*)g, (lv_t*)s, 16, 0, 0);
}

// ---------------- fused f32 -> bf16 convert (all 5 tensors, contiguous dst) ----------
#define F4_HS   2097152u
#define F4_WQ   4194304u
#define F4_WKV  1048576u
__global__ void cvt_all(const float* __restrict__ s0, const float* __restrict__ s1,
                        const float* __restrict__ s2, const float* __restrict__ s3,
                        const float* __restrict__ s4, u16* __restrict__ dst) {
    u32 i = blockIdx.x * 256 + threadIdx.x;   // < 12582912
    const float* src; u32 off;
    if (i < F4_HS)                              { src = s0; off = 0; }
    else if (i < F4_HS + F4_WQ)                 { src = s1; off = F4_HS; }
    else if (i < F4_HS + F4_WQ + F4_WKV)        { src = s2; off = F4_HS + F4_WQ; }
    else if (i < F4_HS + F4_WQ + 2 * F4_WKV)    { src = s3; off = F4_HS + F4_WQ + F4_WKV; }
    else                                        { src = s4; off = F4_HS + F4_WQ + 2 * F4_WKV; }
    float4 v = ((const float4*)src)[i - off];
    union { u16 u[4]; uint2 w; } pk;
    pk.u[0] = f2bf(v.x); pk.u[1] = f2bf(v.y);
    pk.u[2] = f2bf(v.z); pk.u[3] = f2bf(v.w);
    ((uint2*)dst)[i] = pk.w;
}

// ---------------- bf16 GEMM core: 128x128 tile, BK=64 ----------------
#define GEMM_PROLOGUE_AND_MAINLOOP(Aptr, Bptr, Kdim)                                   \
    __shared__ u16 sA[128 * 64];                                                       \
    __shared__ u16 sB[128 * 64];                                                       \
    const int tid = threadIdx.x;                                                       \
    const int w = tid >> 6, lane = tid & 63;                                           \
    const int l15 = lane & 15, quad = lane >> 4;                                       \
    const int m0 = blockIdx.y * 128, n0 = blockIdx.x * 128;                            \
    const int wm = w & 1, wn = w >> 1;                                                 \
    f32x4 acc[4][4];                                                                   \
    _Pragma("unroll") for (int mi = 0; mi < 4; ++mi)                                   \
    _Pragma("unroll") for (int ni = 0; ni < 4; ++ni)                                   \
    _Pragma("unroll") for (int r = 0; r < 4; ++r) acc[mi][ni][r] = 0.f;                \
    for (int kt = 0; kt < (Kdim); kt += 64) {                                          \
        _Pragma("unroll") for (int i = 0; i < 4; ++i) {                                \
            int c = (i * 4 + w) * 64 + lane;                                           \
            int r = c >> 3, sl = c & 7, g = sl ^ (r & 7);                              \
            async16((Aptr) + (size_t)(m0 + r) * (Kdim) + kt + g * 8, &sA[c * 8]);      \
        }                                                                              \
        _Pragma("unroll") for (int i = 0; i < 4; ++i) {                                \
            int c = (i * 4 + w) * 64 + lane;                                           \
            int r = c >> 3, sl = c & 7, g = sl ^ (r & 7);                              \
            async16((Bptr) + (size_t)(n0 + r) * (Kdim) + kt + g * 8, &sB[c * 8]);      \
        }                                                                              \
        __syncthreads();                                                               \
        _Pragma("unroll") for (int ks = 0; ks < 2; ++ks) {                             \
            bf16x8 af[4], bf[4];                                                       \
            _Pragma("unroll") for (int t = 0; t < 4; ++t) {                            \
                int row = wm * 64 + t * 16 + l15;                                      \
                int sl = (ks * 4 + quad) ^ (row & 7);                                  \
                af[t] = *(const bf16x8*)&sA[row * 64 + sl * 8];                        \
            }                                                                          \
            _Pragma("unroll") for (int t = 0; t < 4; ++t) {                            \
                int row = wn * 64 + t * 16 + l15;                                      \
                int sl = (ks * 4 + quad) ^ (row & 7);                                  \
                bf[t] = *(const bf16x8*)&sB[row * 64 + sl * 8];                        \
            }                                                                          \
            _Pragma("unroll") for (int mi = 0; mi < 4; ++mi)                           \
            _Pragma("unroll") for (int ni = 0; ni < 4; ++ni)                           \
                acc[mi][ni] = __builtin_amdgcn_mfma_f32_16x16x32_bf16(                 \
                    af[mi], bf[ni], acc[mi][ni], 0, 0, 0);                             \
        }                                                                              \
        __syncthreads();                                                               \
    }

// Generic: C[M,N] = A[M,K] * B[N,K]^T, f32 out (O-projection)
__global__ __launch_bounds__(256, 2) void gemm_bt_f32(
    const u16* __restrict__ A, const u16* __restrict__ B, float* __restrict__ C,
    int N, int K)
{
    GEMM_PROLOGUE_AND_MAINLOOP(A, B, K)
#pragma unroll
    for (int mi = 0; mi < 4; ++mi) {
        int row = m0 + wm * 64 + mi * 16 + quad * 4;
#pragma unroll
        for (int ni = 0; ni < 4; ++ni) {
            int col = n0 + wn * 64 + ni * 16 + l15;
#pragma unroll
            for (int r = 0; r < 4; ++r)
                C[(size_t)(row + r) * N + col] = acc[mi][ni][r];
        }
    }
}

// Fused QKV: A=[2048,4096] hs, B=[6144,4096] (wq|wk|wv rows), routed output.
__global__ __launch_bounds__(256, 2) void gemm_qkv(
    const u16* __restrict__ A, const u16* __restrict__ B,
    u16* __restrict__ qb, u16* __restrict__ kbuf, u16* __restrict__ vt)
{
    GEMM_PROLOGUE_AND_MAINLOOP(A, B, HIDDEN)
    if (n0 < 4096 + 1024) {   // q or k path: row-major bf16
        u16* outp; int ldo, cb;
        if (n0 < 4096) { outp = qb; ldo = HIDDEN; cb = n0; }
        else           { outp = kbuf; ldo = NKV * HD; cb = n0 - 4096; }
#pragma unroll
        for (int mi = 0; mi < 4; ++mi) {
            int row = m0 + wm * 64 + mi * 16 + quad * 4;
#pragma unroll
            for (int ni = 0; ni < 4; ++ni) {
                int col = cb + wn * 64 + ni * 16 + l15;
#pragma unroll
                for (int r = 0; r < 4; ++r)
                    outp[(size_t)(row + r) * ldo + col] = f2bf(acc[mi][ni][r]);
            }
        }
    } else {                  // v path: transposed vt[c][s]
        int cb = n0 - (4096 + 1024);
#pragma unroll
        for (int mi = 0; mi < 4; ++mi) {
            int row = m0 + wm * 64 + mi * 16 + quad * 4;
#pragma unroll
            for (int ni = 0; ni < 4; ++ni) {
                int c = cb + wn * 64 + ni * 16 + l15;
                union { u16 u[4]; uint2 v; } pk;
#pragma unroll
                for (int r = 0; r < 4; ++r) pk.u[r] = f2bf(acc[mi][ni][r]);
                *(uint2*)&vt[(size_t)c * S_LEN + row] = pk.v;
            }
        }
    }
}

// ---------------- RoPE: f64 table precompute + bf16 apply ----------------
struct DTab { double f[64]; };
__global__ void rope_table(const int* __restrict__ pos, float2* __restrict__ tab,
                           DTab dt) {
    int idx = blockIdx.x * 256 + threadIdx.x;   // < 2048*64
    int d = idx & 63, s = idx >> 6;
    double fr = (double)pos[s] * dt.f[d];
    double sd, cd;
    sincos(fr, &sd, &cd);
    tab[idx] = make_float2((float)cd, (float)sd);
}

#define Q_ITEMS (S_LEN * NH * 64)    // 4194304
__global__ void rope_apply(u16* __restrict__ qb, u16* __restrict__ kb,
                           const float2* __restrict__ tab, float qscale) {
    int idx = blockIdx.x * 256 + threadIdx.x;
    u16* buf; int logH; float osc;
    if (idx < Q_ITEMS) { buf = qb; logH = 5; osc = qscale; }
    else { idx -= Q_ITEMS; buf = kb; logH = 3; osc = 1.0f; }
    int d = idx & 63;
    int rest = idx >> 6;            // = s*H + h
    int s = rest >> logH;
    float2 cs = tab[s * 64 + d];
    float c = cs.x * osc, sn = cs.y * osc;
    u16* p = buf + (size_t)rest * HD + d;
    float x1 = bf2f(p[0]), x2 = bf2f(p[64]);
    p[0]  = f2bf(x1 * c - x2 * sn);
    p[64] = f2bf(x2 * c + x1 * sn);
}

// ---------------- flash attention: 512 thr, q-tile 256, PIPELINED staging ----------
// Pipeline: barrier A (sK reads done) -> issue stageK(next) -> PV -> barrier B
// (sV reads done) -> issue stageV(next). Each barrier's vmcnt(0) drain covers the
// loads issued before it. stage lambdas take the ELEMENT offset k0 = kbi*128.
__global__ __launch_bounds__(512, 1) void attn_kernel(
    const u16* __restrict__ Q, const u16* __restrict__ Kb,
    const u16* __restrict__ Vt, u16* __restrict__ O)
{
    __shared__ u16 sK[128 * 128];                    // 32 KB
    __shared__ u16 sV[128 * 128];                    // 32 KB
    __shared__ __align__(16) u16 sP[8][16 * 264];    // 66 KB, per-wave private
    __shared__ float sAl[8][32];

    const int tid = threadIdx.x;
    const int w = tid >> 6, lane = tid & 63;
    const int l15 = lane & 15, quad = lane >> 4;
    const int h = blockIdx.y, q0 = blockIdx.x * 256;
    const int hk = h >> 2;
    u16* const sPw = sP[w];

    // Q frags (A-operand: m=lane&15, k=quad*8+j); Q pre-scaled by sm_scale*log2e
    bf16x8 qf[2][4];
#pragma unroll
    for (int mt = 0; mt < 2; ++mt)
#pragma unroll
        for (int ks = 0; ks < 4; ++ks)
            qf[mt][ks] = *(const bf16x8*)(Q + (size_t)(q0 + w * 32 + mt * 16 + l15) * HIDDEN
                                           + h * HD + ks * 32 + quad * 8);

    f32x4 oc[8][2];
#pragma unroll
    for (int dt = 0; dt < 8; ++dt)
#pragma unroll
        for (int nt = 0; nt < 2; ++nt)
#pragma unroll
            for (int r = 0; r < 4; ++r) oc[dt][nt][r] = 0.f;
    float m_r[2][4], l_r[2][4];
#pragma unroll
    for (int mt = 0; mt < 2; ++mt)
#pragma unroll
        for (int r = 0; r < 4; ++r) { m_r[mt][r] = -1e30f; l_r[mt][r] = 0.f; }

    // staging: 2048 chunks of 16B per tile, 512 threads x 4; XOR swizzle.
    // k0 is the ELEMENT offset (kbi * 128).
    auto stageK = [&](int k0) {
#pragma unroll
        for (int i = 0; i < 4; ++i) {
            int c = i * 512 + tid;
            int r = c >> 4, sl = c & 15, g = sl ^ (r & 15);
            async16(Kb + (size_t)(k0 + r) * (NKV * HD) + hk * HD + g * 8, &sK[c * 8]);
        }
    };
    auto stageV = [&](int k0) {
#pragma unroll
        for (int i = 0; i < 4; ++i) {
            int c = i * 512 + tid;
            int r = c >> 4, sl = c & 15, g = sl ^ (r & 15);
            async16(Vt + (size_t)(hk * HD + r) * S_LEN + k0 + g * 8, &sV[c * 8]);
        }
    };

    stageK(0);
    stageV(0);
    __syncthreads();

    for (int kbi = 0; kbi < 16; ++kbi) {
        // ---- S = Q K^T from sK ----
        f32x4 sa[2][8];
#pragma unroll
        for (int mt = 0; mt < 2; ++mt)
#pragma unroll
            for (int nt = 0; nt < 8; ++nt)
#pragma unroll
                for (int r = 0; r < 4; ++r) sa[mt][nt][r] = 0.f;
#pragma unroll
        for (int ks = 0; ks < 4; ++ks) {
            bf16x8 kf[8];
#pragma unroll
            for (int nt = 0; nt < 8; ++nt) {
                int row = nt * 16 + l15;
                int sl = (ks * 4 + quad) ^ (row & 15);
                kf[nt] = *(const bf16x8*)&sK[row * 128 + sl * 8];
            }
#pragma unroll
            for (int mt = 0; mt < 2; ++mt)
#pragma unroll
                for (int nt = 0; nt < 8; ++nt)
                    sa[mt][nt] = __builtin_amdgcn_mfma_f32_16x16x32_bf16(
                        qf[mt][ks], kf[nt], sa[mt][nt], 0, 0, 0);
        }

        // ---- online softmax (DPP reductions, exp2 domain) ----
#pragma unroll
        for (int mt = 0; mt < 2; ++mt)
#pragma unroll
            for (int r = 0; r < 4; ++r) {
                float mx = sa[mt][0][r];
#pragma unroll
                for (int nt = 1; nt < 8; ++nt) mx = fmaxf(mx, sa[mt][nt][r]);
                mx = row_max16(mx);
                float mnew = fmaxf(m_r[mt][r], mx);
                float alpha = fexp2(m_r[mt][r] - mnew);
                m_r[mt][r] = mnew;
                int ql = mt * 16 + quad * 4 + r;
                // chunk-major P: (q,k) at (k>>3)*264 + q*8 + (k&7); k = nt*16+l15
                u16* pb = sPw + (l15 >> 3) * 264 + ql * 8 + (l15 & 7);
                float rs = 0.f;
#pragma unroll
                for (int nt = 0; nt < 8; ++nt) {
                    float p = fexp2(sa[mt][nt][r] - mnew);
                    rs += p;
                    pb[nt * 528] = f2bf(p);
                }
                rs = row_sum16(rs);
                l_r[mt][r] = l_r[mt][r] * alpha + rs;
                if (l15 == 0) sAl[w][ql] = alpha;
            }

        __syncthreads();                    // A: all sK reads done; prior stageV drained
        if (kbi < 15) stageK((kbi + 1) * 128);

        // ---- rescale O^T acc (wave-local) ----
        float al0 = sAl[w][l15], al1 = sAl[w][16 + l15];
#pragma unroll
        for (int dt = 0; dt < 8; ++dt)
#pragma unroll
            for (int r = 0; r < 4; ++r) { oc[dt][0][r] *= al0; oc[dt][1][r] *= al1; }

        // ---- O^T += V^T P^T from sV, sPw ----
#pragma unroll
        for (int ks = 0; ks < 4; ++ks) {
            bf16x8 vf[8], pf[2];
#pragma unroll
            for (int dt = 0; dt < 8; ++dt) {
                int row = dt * 16 + l15;
                int sl = (ks * 4 + quad) ^ (row & 15);
                vf[dt] = *(const bf16x8*)&sV[row * 128 + sl * 8];
            }
#pragma unroll
            for (int nt = 0; nt < 2; ++nt)
                pf[nt] = *(const bf16x8*)&sPw[(ks * 4 + quad) * 264 + (nt * 16 + l15) * 8];
#pragma unroll
            for (int dt = 0; dt < 8; ++dt)
#pragma unroll
                for (int nt = 0; nt < 2; ++nt)
                    oc[dt][nt] = __builtin_amdgcn_mfma_f32_16x16x32_bf16(
                        vf[dt], pf[nt], oc[dt][nt], 0, 0, 0);
        }

        __syncthreads();                    // B: all sV reads done; stageK drained
        if (kbi < 15) stageV((kbi + 1) * 128);
    }

    // ---- finalize: normalize, store O[q][h*128+d] bf16 ----
#pragma unroll
    for (int mt = 0; mt < 2; ++mt)
#pragma unroll
        for (int r = 0; r < 4; ++r)
            if (l15 == 0) sAl[w][mt * 16 + quad * 4 + r] = l_r[mt][r];
    float il[2];
    il[0] = 1.f / sAl[w][l15];
    il[1] = 1.f / sAl[w][16 + l15];
#pragma unroll
    for (int nt = 0; nt < 2; ++nt)
#pragma unroll
        for (int dt = 0; dt < 8; ++dt) {
            union { u16 u[4]; uint2 v; } pk;
#pragma unroll
            for (int r = 0; r < 4; ++r) pk.u[r] = f2bf(oc[dt][nt][r] * il[nt]);
            *(uint2*)(O + (size_t)(q0 + w * 32 + nt * 16 + l15) * HIDDEN
                        + h * HD + dt * 16 + quad * 4) = pk.v;
        }
}

// ---------------- host ----------------
extern "C" void kernel_launch(void* const* d_in, const int* in_sizes, int n_in,
                              void* d_out, int out_size, void* d_ws, size_t ws_size,
                              hipStream_t stream) {
    const float* hs = (const float*)d_in[0];
    const int* pos  = (const int*)d_in[1];
    const float* wq = (const float*)d_in[2];
    const float* wk = (const float*)d_in[3];
    const float* wv = (const float*)d_in[4];
    const float* wo = (const float*)d_in[5];
    float* out = (float*)d_out;

    u16* ws    = (u16*)d_ws;
    u16* hid16 = ws;
    u16* wq16  = hid16 + (size_t)S_LEN * HIDDEN;          // hid|wq|wk|wv|wo contiguous
    u16* wk16  = wq16 + (size_t)HIDDEN * HIDDEN;
    u16* wv16  = wk16 + (size_t)NKV * HD * HIDDEN;
    u16* wo16  = wv16 + (size_t)NKV * HD * HIDDEN;
    u16* qb    = wo16 + (size_t)HIDDEN * HIDDEN;
    u16* kb    = qb + (size_t)S_LEN * HIDDEN;
    u16* vt    = kb + (size_t)S_LEN * NKV * HD;
    u16* at    = vt + (size_t)S_LEN * NKV * HD;
    float2* tab = (float2*)(at + (size_t)S_LEN * HIDDEN);

    dim3 blk(256);

    // one fused convert: 12582912 float4s -> contiguous bf16 region at hid16
    cvt_all<<<dim3(12582912u / 256), blk, 0, stream>>>(hs, wq, wk, wv, wo, hid16);

    // fused QKV projection (V written transposed)
    gemm_qkv<<<dim3((HIDDEN + 2 * NKV * HD) / 128, S_LEN / 128), blk, 0, stream>>>(
        hid16, wq16, qb, kb, vt);

    DTab dt;
    for (int i = 0; i < 64; ++i) dt.f[i] = pow(500000.0, -(double)i / 64.0);
    const float qscale = 0.08838834764831845f * 1.4426950408889634f; // sm_scale*log2e
    rope_table<<<dim3(S_LEN * 64 / 256), blk, 0, stream>>>(pos, tab, dt);
    rope_apply<<<dim3((Q_ITEMS + S_LEN * NKV * 64) / 256), blk, 0, stream>>>(
        qb, kb, tab, qscale);

    attn_kernel<<<dim3(S_LEN / 256, NH), dim3(512), 0, stream>>>(qb, kb, vt, at);

    gemm_bt_f32<<<dim3(HIDDEN / 128, S_LEN / 128), blk, 0, stream>>>(
        at, wo16, out, HIDDEN, HIDDEN);
}